// Round 2
// baseline (316.701 us; speedup 1.0000x reference)
//
#include <hip/hip_runtime.h>
#include <hip/hip_bf16.h>
#include <math.h>

// Problem constants
#define BN    8        // b*n = 4*2
#define H     480
#define W     640
#define CH    128
#define OH    120      // conv out h (stride 4, pad 3, k 7)
#define OW    160      // conv out w
#define P     192
#define PS    7
#define GH    16
#define GW    16
#define PH    30       // cell height  (480/16)
#define PW    40       // cell width   (640/16)

// ---------------------------------------------------------------------------
// Kernel 1: conv encoder fmap only (1->128ch, 7x7, stride 4, pad 3, +b, ReLU)
// One thread per output pixel; 49-tap input patch in registers; loop 128 ch.
// ---------------------------------------------------------------------------
__global__ __launch_bounds__(256) void conv_enc(
    const float* __restrict__ f,
    const float* __restrict__ wf, const float* __restrict__ bf,
    float* __restrict__ fmap)
{
    int pix = blockIdx.x * blockDim.x + threadIdx.x;
    if (pix >= BN * OH * OW) return;
    int ox = pix % OW;
    int t  = pix / OW;
    int oy = t % OH;
    int b  = t / OH;

    const float* fb = f + (size_t)b * H * W;
    int iy0 = 4 * oy - 3;
    int ix0 = 4 * ox - 3;

    float in[49];
    if (oy > 0 && ox > 0) {
        // interior: 4*oy-3 >= 1, max 4*119+3 = 479 -> always in range
        #pragma unroll
        for (int ky = 0; ky < 7; ky++) {
            const float* row = fb + (iy0 + ky) * W + ix0;
            #pragma unroll
            for (int kx = 0; kx < 7; kx++) in[ky * 7 + kx] = row[kx];
        }
    } else {
        #pragma unroll
        for (int ky = 0; ky < 7; ky++) {
            int iy = iy0 + ky;
            #pragma unroll
            for (int kx = 0; kx < 7; kx++) {
                int ix = ix0 + kx;
                in[ky * 7 + kx] = (iy >= 0 && ix >= 0) ? fb[iy * W + ix] : 0.0f;
            }
        }
    }

    size_t obase = (size_t)b * CH * (OH * OW) + (size_t)oy * OW + ox;
    for (int c = 0; c < CH; c++) {
        const float* wfc = wf + c * 49;
        float af = bf[c];
        #pragma unroll
        for (int k = 0; k < 49; k++) af = fmaf(wfc[k], in[k], af);
        fmap[obase + (size_t)c * (OH * OW)] = fmaxf(af, 0.0f);
    }
}

// ---------------------------------------------------------------------------
// Kernel 2: fused Harris + per-cell argmax. One block per grid cell (30x40).
// Computes response locally (never materializes g), reduces to (cval, cidx).
// dx/dy reflect-padded at right/bottom image edge; box window zero-padded.
// In-cell linear index = iy*40+ix (row-major), ties -> smallest index.
// ---------------------------------------------------------------------------
__global__ __launch_bounds__(256) void harris_cell(
    const float* __restrict__ f, float* __restrict__ cval, int* __restrict__ cidx)
{
    __shared__ float sf[37][48];
    __shared__ float dxx[36][48], dyy[36][48], dxy[36][48];
    __shared__ float sv[256];
    __shared__ int   si[256];

    int cell = blockIdx.x;            // b*256 + gh*16 + gw
    int b  = cell >> 8;
    int ci = cell & 255;
    int gh = ci >> 4, gw = ci & 15;
    int cy0 = gh * PH, cx0 = gw * PW;
    const float* fb = f + (size_t)b * H * W;
    int tid = threadIdx.x;

    // load f rows [cy0-3, cy0+33] (37), cols [cx0-3, cx0+43] (47), clamped
    for (int i = tid; i < 37 * 47; i += 256) {
        int r = i / 47, c = i % 47;
        int y = min(max(cy0 - 3 + r, 0), H - 1);
        int x = min(max(cx0 - 3 + c, 0), W - 1);
        sf[r][c] = fb[(size_t)y * W + x];
    }
    __syncthreads();

    // derivative products at rows [cy0-3, cy0+32] (36), cols [cx0-3, cx0+42] (46)
    for (int i = tid; i < 36 * 46; i += 256) {
        int r = i / 46, c = i % 46;
        int y = cy0 - 3 + r;
        int x = cx0 - 3 + c;
        float vxx = 0.0f, vyy = 0.0f, vxy = 0.0f;
        if (y >= 0 && y < H && x >= 0 && x < W) {
            int xa = (x == W - 1) ? (x - 2) : x;    // dx[639] = dx[637]
            int ya = (y == H - 1) ? (y - 2) : y;    // dy[479] = dy[477]
            int lx = xa - (cx0 - 3);
            int ly = ya - (cy0 - 3);
            float dxv = sf[r][lx + 1] - sf[r][lx];
            float dyv = sf[ly + 1][c] - sf[ly][c];
            vxx = dxv * dxv;
            vyy = dyv * dyv;
            vxy = dxv * dyv;
        }
        dxx[r][c] = vxx; dyy[r][c] = vyy; dxy[r][c] = vxy;
    }
    __syncthreads();

    // per-pixel direct 7x7 box sums + response + local argmax
    float best = -INFINITY;
    int   bidx = 0x7fffffff;
    for (int i = tid; i < PH * PW; i += 256) {
        int iy = i / PW, ix = i % PW;
        float Sxx = 0.0f, Syy = 0.0f, Sxy = 0.0f;
        #pragma unroll
        for (int ky = 0; ky < 7; ky++) {
            #pragma unroll
            for (int kx = 0; kx < 7; kx++) {
                Sxx += dxx[iy + ky][ix + kx];
                Syy += dyy[iy + ky][ix + kx];
                Sxy += dxy[iy + ky][ix + kx];
            }
        }
        float Ixx = Sxx / 49.0f;
        float Iyy = Syy / 49.0f;
        float Ixy = Sxy / 49.0f;
        float resp = (Ixx * Iyy - Ixy * Ixy) / (Ixx + Iyy + 1e-8f);
        if (resp > best) { best = resp; bidx = i; }
    }

    sv[tid] = best;
    si[tid] = bidx;
    __syncthreads();
    for (int s = 128; s > 0; s >>= 1) {
        if (tid < s) {
            float ov = sv[tid + s];
            int   oi = si[tid + s];
            if (ov > sv[tid] || (ov == sv[tid] && oi < si[tid])) {
                sv[tid] = ov; si[tid] = oi;
            }
        }
        __syncthreads();
    }
    if (tid == 0) { cval[cell] = sv[0]; cidx[cell] = si[0]; }
}

// ---------------------------------------------------------------------------
// Kernel 3: stable top-192 of 256 cell maxima per batch via O(256^2) ranking
// (descending, ties -> ascending index == lax.top_k semantics).
// ---------------------------------------------------------------------------
__global__ __launch_bounds__(256) void topk_coords(
    const float* __restrict__ cval, const int* __restrict__ cidx,
    float* __restrict__ coords)
{
    int b = blockIdx.x;
    int j = threadIdx.x;
    __shared__ float v[256];
    v[j] = cval[b * 256 + j];
    __syncthreads();
    float vj = v[j];
    int rank = 0;
    for (int k = 0; k < 256; k++) {
        float vk = v[k];
        rank += (vk > vj) || (vk == vj && k < j);
    }
    if (rank < P) {
        int ii = cidx[b * 256 + j];
        int gh = j >> 4, gw = j & 15;
        int y = ii / PW + gh * PH;
        int x = ii % PW + gw * PW;
        coords[((size_t)b * P + rank) * 2 + 0] = (float)x;
        coords[((size_t)b * P + rank) * 2 + 1] = (float)y;
    }
}

// ---------------------------------------------------------------------------
// Kernel 4: patches. One block per (b,p) point.
// patches_f: 49 offsets x 128 ch bilinear from fmap.
// patches_c: center bilinear on the SECOND conv map, computed on the fly
//            (4 output pixels x 128 ch, 14x14 input patch in LDS).
// ---------------------------------------------------------------------------
__device__ __forceinline__ float samp(const float* img, int x, int y)
{
    return (x >= 0 && x < OW && y >= 0 && y < OH) ? img[y * OW + x] : 0.0f;
}

__global__ __launch_bounds__(256) void patches_kern(
    const float* __restrict__ coords,
    const float* __restrict__ fmap,
    const float* __restrict__ frame,
    const float* __restrict__ wc, const float* __restrict__ bc,
    float* __restrict__ pf, float* __restrict__ pc)
{
    __shared__ int   sx0[49], sy0[49];
    __shared__ float sw0[49], sw1[49], sw2[49], sw3[49];
    __shared__ float sf2[14][16];
    __shared__ float vq[128][5];

    int bp = blockIdx.x;               // 0 .. BN*P
    int b = bp / P;
    float cx = coords[(size_t)bp * 2 + 0] * 0.25f;   // /DS, exact
    float cy = coords[(size_t)bp * 2 + 1] * 0.25f;
    int tid = threadIdx.x;

    if (tid < 49) {
        int ky = tid / 7, kx = tid % 7;
        float xs = cx + (float)(kx - 3);
        float ys = cy + (float)(ky - 3);
        float x0 = floorf(xs), y0 = floorf(ys);
        float wx = xs - x0, wy = ys - y0;
        sx0[tid] = (int)x0;
        sy0[tid] = (int)y0;
        sw0[tid] = (1.0f - wx) * (1.0f - wy);
        sw1[tid] = wx * (1.0f - wy);
        sw2[tid] = (1.0f - wx) * wy;
        sw3[tid] = wx * wy;
    }

    // stage 14x14 input patch for the on-the-fly conv (zero outside image)
    int xi = (int)floorf(cx), yi = (int)floorf(cy);
    int ix0 = 4 * xi - 3, iy0 = 4 * yi - 3;
    const float* frb = frame + (size_t)b * H * W;
    for (int i = tid; i < 14 * 14; i += 256) {
        int r = i / 14, c = i % 14;
        int y = iy0 + r, x = ix0 + c;
        sf2[r][c] = (y >= 0 && y < H && x >= 0 && x < W)
                  ? frb[(size_t)y * W + x] : 0.0f;
    }
    __syncthreads();

    // ---- patches_f from fmap ----
    const float* fm = fmap + (size_t)b * CH * (OH * OW);
    size_t pfbase = (size_t)bp * CH * 49;
    for (int idx = tid; idx < CH * 49; idx += 256) {
        int c = idx / 49;
        int k = idx - c * 49;
        const float* fc = fm + (size_t)c * (OH * OW);
        int x0 = sx0[k], y0 = sy0[k];
        float acc = sw0[k] * samp(fc, x0,     y0)
                  + sw1[k] * samp(fc, x0 + 1, y0)
                  + sw2[k] * samp(fc, x0,     y0 + 1)
                  + sw3[k] * samp(fc, x0 + 1, y0 + 1);
        pf[pfbase + idx] = acc;
    }

    // ---- on-the-fly second conv at the 4 corner pixels ----
    for (int idx = tid; idx < 512; idx += 256) {
        int q = idx & 3;            // q: (qx,qy) = (q&1, q>>1)
        int c = idx >> 2;
        int qx = q & 1, qy = q >> 1;
        const float* wcc = wc + c * 49;
        float acc = bc[c];
        #pragma unroll
        for (int ky = 0; ky < 7; ky++) {
            #pragma unroll
            for (int kx = 0; kx < 7; kx++)
                acc = fmaf(wcc[ky * 7 + kx], sf2[4 * qy + ky][4 * qx + kx], acc);
        }
        vq[c][q] = fmaxf(acc, 0.0f);
    }
    __syncthreads();

    // ---- patches_c: bilinear combine with boundary masks ----
    float wx = cx - floorf(cx), wy = cy - floorf(cy);
    float m00 = (xi >= 0 && xi < OW && yi >= 0 && yi < OH) ? 1.0f : 0.0f;
    float m10 = (xi + 1 >= 0 && xi + 1 < OW && yi >= 0 && yi < OH) ? 1.0f : 0.0f;
    float m01 = (xi >= 0 && xi < OW && yi + 1 >= 0 && yi + 1 < OH) ? 1.0f : 0.0f;
    float m11 = (xi + 1 >= 0 && xi + 1 < OW && yi + 1 >= 0 && yi + 1 < OH) ? 1.0f : 0.0f;
    float w00 = (1.0f - wx) * (1.0f - wy) * m00;
    float w10 = wx * (1.0f - wy) * m10;
    float w01 = (1.0f - wx) * wy * m01;
    float w11 = wx * wy * m11;
    if (tid < CH) {
        float acc = w00 * vq[tid][0] + w10 * vq[tid][1]
                  + w01 * vq[tid][2] + w11 * vq[tid][3];
        pc[(size_t)bp * CH + tid] = acc;
    }
}

// ---------------------------------------------------------------------------
// Launch
// ---------------------------------------------------------------------------
extern "C" void kernel_launch(void* const* d_in, const int* in_sizes, int n_in,
                              void* d_out, int out_size, void* d_ws, size_t ws_size,
                              hipStream_t stream)
{
    const float* frame = (const float*)d_in[0];
    const float* w_f   = (const float*)d_in[1];
    const float* b_f   = (const float*)d_in[2];
    const float* w_c   = (const float*)d_in[3];
    const float* b_c   = (const float*)d_in[4];

    float* out = (float*)d_out;
    // output layout: coords | patches_f | patches_c | fmap
    const size_t coords_sz = (size_t)BN * P * 2;                 // 3072
    const size_t pf_sz     = (size_t)BN * P * CH * 49;           // 9,633,792
    const size_t pc_sz     = (size_t)BN * P * CH;                // 196,608
    float* coords = out;
    float* pf     = out + coords_sz;
    float* pc     = out + coords_sz + pf_sz;
    float* fmap   = out + coords_sz + pf_sz + pc_sz;

    // workspace: only cell argmax state (16 KB)
    float* cval = (float*)d_ws;                                  // 2048 f
    int*   cidx = (int*)(cval + BN * 256);                       // 2048 i

    conv_enc<<<(BN * OH * OW) / 256, 256, 0, stream>>>(frame, w_f, b_f, fmap);

    harris_cell<<<BN * 256, 256, 0, stream>>>(frame, cval, cidx);

    topk_coords<<<BN, 256, 0, stream>>>(cval, cidx, coords);

    patches_kern<<<BN * P, 256, 0, stream>>>(
        coords, fmap, frame, w_c, b_c, pf, pc);
}

// Round 3
// 277.729 us; speedup vs baseline: 1.1403x; 1.1403x over previous
//
#include <hip/hip_runtime.h>
#include <hip/hip_bf16.h>
#include <math.h>

// Problem constants
#define BN    8        // b*n = 4*2
#define H     480
#define W     640
#define CH    128
#define OH    120      // conv out h (stride 4, pad 3, k 7)
#define OW    160      // conv out w
#define P     192
#define PS    7
#define GH    16
#define GW    16
#define PH    30       // cell height  (480/16)
#define PW    40       // cell width   (640/16)

// ---------------------------------------------------------------------------
// Kernel 1: conv encoder fmap (1->128ch, 7x7, stride 4, pad 3, +b, ReLU).
// One thread per output pixel x 16-channel group; grid 600x8 blocks so the
// machine has 8 waves/SIMD to hide scalar-weight-load latency.
// ---------------------------------------------------------------------------
__global__ __launch_bounds__(256) void conv_enc(
    const float* __restrict__ f,
    const float* __restrict__ wf, const float* __restrict__ bf,
    float* __restrict__ fmap)
{
    int pix = blockIdx.x * blockDim.x + threadIdx.x;
    if (pix >= BN * OH * OW) return;
    int c0 = blockIdx.y * 16;            // channel group
    int ox = pix % OW;
    int t  = pix / OW;
    int oy = t % OH;
    int b  = t / OH;

    const float* fb = f + (size_t)b * H * W;
    int iy0 = 4 * oy - 3;
    int ix0 = 4 * ox - 3;

    float in[49];
    if (oy > 0 && ox > 0) {
        // interior: 4*oy-3 >= 1, max 4*119+3 = 479 -> always in range
        #pragma unroll
        for (int ky = 0; ky < 7; ky++) {
            const float* row = fb + (iy0 + ky) * W + ix0;
            #pragma unroll
            for (int kx = 0; kx < 7; kx++) in[ky * 7 + kx] = row[kx];
        }
    } else {
        #pragma unroll
        for (int ky = 0; ky < 7; ky++) {
            int iy = iy0 + ky;
            #pragma unroll
            for (int kx = 0; kx < 7; kx++) {
                int ix = ix0 + kx;
                in[ky * 7 + kx] = (iy >= 0 && ix >= 0) ? fb[iy * W + ix] : 0.0f;
            }
        }
    }

    size_t obase = (size_t)b * CH * (OH * OW) + (size_t)oy * OW + ox;
    #pragma unroll 2
    for (int c = c0; c < c0 + 16; c++) {
        const float* wfc = wf + c * 49;
        float af = bf[c];
        #pragma unroll
        for (int k = 0; k < 49; k++) af = fmaf(wfc[k], in[k], af);
        fmap[obase + (size_t)c * (OH * OW)] = fmaxf(af, 0.0f);
    }
}

// ---------------------------------------------------------------------------
// Kernel 2: fused Harris + per-cell argmax. One block per grid cell (30x40).
// ---------------------------------------------------------------------------
__global__ __launch_bounds__(256) void harris_cell(
    const float* __restrict__ f, float* __restrict__ cval, int* __restrict__ cidx)
{
    __shared__ float sf[37][48];
    __shared__ float dxx[36][48], dyy[36][48], dxy[36][48];
    __shared__ float sv[256];
    __shared__ int   si[256];

    int cell = blockIdx.x;            // b*256 + gh*16 + gw
    int b  = cell >> 8;
    int ci = cell & 255;
    int gh = ci >> 4, gw = ci & 15;
    int cy0 = gh * PH, cx0 = gw * PW;
    const float* fb = f + (size_t)b * H * W;
    int tid = threadIdx.x;

    // load f rows [cy0-3, cy0+33] (37), cols [cx0-3, cx0+43] (47), clamped
    for (int i = tid; i < 37 * 47; i += 256) {
        int r = i / 47, c = i % 47;
        int y = min(max(cy0 - 3 + r, 0), H - 1);
        int x = min(max(cx0 - 3 + c, 0), W - 1);
        sf[r][c] = fb[(size_t)y * W + x];
    }
    __syncthreads();

    // derivative products at rows [cy0-3, cy0+32] (36), cols [cx0-3, cx0+42] (46)
    for (int i = tid; i < 36 * 46; i += 256) {
        int r = i / 46, c = i % 46;
        int y = cy0 - 3 + r;
        int x = cx0 - 3 + c;
        float vxx = 0.0f, vyy = 0.0f, vxy = 0.0f;
        if (y >= 0 && y < H && x >= 0 && x < W) {
            int xa = (x == W - 1) ? (x - 2) : x;    // dx[639] = dx[637]
            int ya = (y == H - 1) ? (y - 2) : y;    // dy[479] = dy[477]
            int lx = xa - (cx0 - 3);
            int ly = ya - (cy0 - 3);
            float dxv = sf[r][lx + 1] - sf[r][lx];
            float dyv = sf[ly + 1][c] - sf[ly][c];
            vxx = dxv * dxv;
            vyy = dyv * dyv;
            vxy = dxv * dyv;
        }
        dxx[r][c] = vxx; dyy[r][c] = vyy; dxy[r][c] = vxy;
    }
    __syncthreads();

    // per-pixel direct 7x7 box sums + response + local argmax
    float best = -INFINITY;
    int   bidx = 0x7fffffff;
    for (int i = tid; i < PH * PW; i += 256) {
        int iy = i / PW, ix = i % PW;
        float Sxx = 0.0f, Syy = 0.0f, Sxy = 0.0f;
        #pragma unroll
        for (int ky = 0; ky < 7; ky++) {
            #pragma unroll
            for (int kx = 0; kx < 7; kx++) {
                Sxx += dxx[iy + ky][ix + kx];
                Syy += dyy[iy + ky][ix + kx];
                Sxy += dxy[iy + ky][ix + kx];
            }
        }
        float Ixx = Sxx / 49.0f;
        float Iyy = Syy / 49.0f;
        float Ixy = Sxy / 49.0f;
        float resp = (Ixx * Iyy - Ixy * Ixy) / (Ixx + Iyy + 1e-8f);
        if (resp > best) { best = resp; bidx = i; }
    }

    sv[tid] = best;
    si[tid] = bidx;
    __syncthreads();
    for (int s = 128; s > 0; s >>= 1) {
        if (tid < s) {
            float ov = sv[tid + s];
            int   oi = si[tid + s];
            if (ov > sv[tid] || (ov == sv[tid] && oi < si[tid])) {
                sv[tid] = ov; si[tid] = oi;
            }
        }
        __syncthreads();
    }
    if (tid == 0) { cval[cell] = sv[0]; cidx[cell] = si[0]; }
}

// ---------------------------------------------------------------------------
// Kernel 3: stable top-192 of 256 cell maxima per batch via O(256^2) ranking
// ---------------------------------------------------------------------------
__global__ __launch_bounds__(256) void topk_coords(
    const float* __restrict__ cval, const int* __restrict__ cidx,
    float* __restrict__ coords)
{
    int b = blockIdx.x;
    int j = threadIdx.x;
    __shared__ float v[256];
    v[j] = cval[b * 256 + j];
    __syncthreads();
    float vj = v[j];
    int rank = 0;
    for (int k = 0; k < 256; k++) {
        float vk = v[k];
        rank += (vk > vj) || (vk == vj && k < j);
    }
    if (rank < P) {
        int ii = cidx[b * 256 + j];
        int gh = j >> 4, gw = j & 15;
        int y = ii / PW + gh * PH;
        int x = ii % PW + gw * PW;
        coords[((size_t)b * P + rank) * 2 + 0] = (float)x;
        coords[((size_t)b * P + rank) * 2 + 1] = (float)y;
    }
}

// ---------------------------------------------------------------------------
// Kernel 4: patches. One block per (b,p) point.
// coords are multiples of 0.25 and patch offsets are integers, so all 49
// taps share one bilinear fraction (wx,wy) and the sample window is exactly
// 8x8. Stage 8x8x128 of fmap in LDS (zero-filled OOB), compute from LDS.
// patches_c: on-the-fly second conv at the 4 corner pixels.
// ---------------------------------------------------------------------------
__global__ __launch_bounds__(256) void patches_kern(
    const float* __restrict__ coords,
    const float* __restrict__ fmap,
    const float* __restrict__ frame,
    const float* __restrict__ wc, const float* __restrict__ bc,
    float* __restrict__ pf, float* __restrict__ pc)
{
    __shared__ float sfm[CH][64];      // 8 rows x 8 cols per channel, 32 KB
    __shared__ float sf2[14][16];
    __shared__ float vq[CH][5];

    int bp = blockIdx.x;               // 0 .. BN*P
    int b = bp / P;
    float cx = coords[(size_t)bp * 2 + 0] * 0.25f;   // /DS, exact
    float cy = coords[(size_t)bp * 2 + 1] * 0.25f;
    int tid = threadIdx.x;

    int X0 = (int)floorf(cx), Y0 = (int)floorf(cy);
    float wx = cx - (float)X0, wy = cy - (float)Y0;
    float w00 = (1.0f - wx) * (1.0f - wy);
    float w10 = wx * (1.0f - wy);
    float w01 = (1.0f - wx) * wy;
    float w11 = wx * wy;

    // stage fmap window rows [Y0-3, Y0+4], cols [X0-3, X0+4], all channels
    const float* fm = fmap + (size_t)b * CH * (OH * OW);
    for (int i = tid; i < CH * 64; i += 256) {
        int ch = i >> 6;
        int off = i & 63;
        int r = off >> 3, c = off & 7;
        int gy = Y0 - 3 + r, gx = X0 - 3 + c;
        sfm[ch][off] = (gy >= 0 && gy < OH && gx >= 0 && gx < OW)
                     ? fm[(size_t)ch * (OH * OW) + gy * OW + gx] : 0.0f;
    }

    // stage 14x14 input patch for the on-the-fly conv (zero outside image)
    int ix0 = 4 * X0 - 3, iy0 = 4 * Y0 - 3;
    const float* frb = frame + (size_t)b * H * W;
    for (int i = tid; i < 14 * 14; i += 256) {
        int r = i / 14, c = i % 14;
        int y = iy0 + r, x = ix0 + c;
        sf2[r][c] = (y >= 0 && y < H && x >= 0 && x < W)
                  ? frb[(size_t)y * W + x] : 0.0f;
    }
    __syncthreads();

    // ---- patches_f: bilinear from LDS ----
    size_t pfbase = (size_t)bp * CH * 49;
    for (int idx = tid; idx < CH * 49; idx += 256) {
        int c = idx / 49;
        int k = idx - c * 49;
        int ky = k / 7, kx = k - ky * 7;
        int o = ky * 8 + kx;
        float acc = w00 * sfm[c][o]
                  + w10 * sfm[c][o + 1]
                  + w01 * sfm[c][o + 8]
                  + w11 * sfm[c][o + 9];
        pf[pfbase + idx] = acc;
    }

    // ---- on-the-fly second conv at the 4 corner pixels ----
    for (int idx = tid; idx < 512; idx += 256) {
        int q = idx & 3;            // (qx,qy) = (q&1, q>>1)
        int c = idx >> 2;
        int qx = q & 1, qy = q >> 1;
        const float* wcc = wc + c * 49;
        float acc = bc[c];
        #pragma unroll
        for (int ky = 0; ky < 7; ky++) {
            #pragma unroll
            for (int kx = 0; kx < 7; kx++)
                acc = fmaf(wcc[ky * 7 + kx], sf2[4 * qy + ky][4 * qx + kx], acc);
        }
        vq[c][q] = fmaxf(acc, 0.0f);
    }
    __syncthreads();

    // ---- patches_c: bilinear combine with boundary masks ----
    float m00 = (X0 >= 0 && X0 < OW && Y0 >= 0 && Y0 < OH) ? 1.0f : 0.0f;
    float m10 = (X0 + 1 >= 0 && X0 + 1 < OW && Y0 >= 0 && Y0 < OH) ? 1.0f : 0.0f;
    float m01 = (X0 >= 0 && X0 < OW && Y0 + 1 >= 0 && Y0 + 1 < OH) ? 1.0f : 0.0f;
    float m11 = (X0 + 1 >= 0 && X0 + 1 < OW && Y0 + 1 >= 0 && Y0 + 1 < OH) ? 1.0f : 0.0f;
    if (tid < CH) {
        float acc = w00 * m00 * vq[tid][0] + w10 * m10 * vq[tid][1]
                  + w01 * m01 * vq[tid][2] + w11 * m11 * vq[tid][3];
        pc[(size_t)bp * CH + tid] = acc;
    }
}

// ---------------------------------------------------------------------------
// Launch
// ---------------------------------------------------------------------------
extern "C" void kernel_launch(void* const* d_in, const int* in_sizes, int n_in,
                              void* d_out, int out_size, void* d_ws, size_t ws_size,
                              hipStream_t stream)
{
    const float* frame = (const float*)d_in[0];
    const float* w_f   = (const float*)d_in[1];
    const float* b_f   = (const float*)d_in[2];
    const float* w_c   = (const float*)d_in[3];
    const float* b_c   = (const float*)d_in[4];

    float* out = (float*)d_out;
    // output layout: coords | patches_f | patches_c | fmap
    const size_t coords_sz = (size_t)BN * P * 2;                 // 3072
    const size_t pf_sz     = (size_t)BN * P * CH * 49;           // 9,633,792
    const size_t pc_sz     = (size_t)BN * P * CH;                // 196,608
    float* coords = out;
    float* pf     = out + coords_sz;
    float* pc     = out + coords_sz + pf_sz;
    float* fmap   = out + coords_sz + pf_sz + pc_sz;

    // workspace: only cell argmax state (16 KB)
    float* cval = (float*)d_ws;                                  // 2048 f
    int*   cidx = (int*)(cval + BN * 256);                       // 2048 i

    dim3 cg((BN * OH * OW) / 256, 8);
    conv_enc<<<cg, 256, 0, stream>>>(frame, w_f, b_f, fmap);

    harris_cell<<<BN * 256, 256, 0, stream>>>(frame, cval, cidx);

    topk_coords<<<BN, 256, 0, stream>>>(cval, cidx, coords);

    patches_kern<<<BN * P, 256, 0, stream>>>(
        coords, fmap, frame, w_c, b_c, pf, pc);
}